// Round 1
// baseline (722.967 us; speedup 1.0000x reference)
//
#include <hip/hip_runtime.h>

// Adding-doubling radiative transfer: B=2048 cols, N=60 layers, C=128 channels.
// One thread per (b,c) column; all layer recurrences serial per thread.
//
// Register-pressure restructure vs previous version (which kept rs[60]+rt[59]+
// absD[59] = 178 floats live -> VGPR=256 + ~130 MiB scratch spills, 11.7% occ):
//   * ONE arr[60]: holds rs[] after phase A; rt[] overwrites it in place during
//     phase B (rs[m] is dead before rt[m] is written).
//   * absorbed down-contribution written to global in phase B; phase C does
//     absorbed[i] += up-part (same-thread RMW, L2-resident reuse window).
// Peak live state ~60 floats + scalars.

#define NL 60
#define CC 128

__global__ __launch_bounds__(256) void adding_doubling_kernel(
    const float* __restrict__ a, const float* __restrict__ r,
    const float* __restrict__ t, const float* __restrict__ s,
    float* __restrict__ flux_down, float* __restrict__ flux_up,
    float* __restrict__ absorbed, int ncol)
{
    const int tid = blockIdx.x * blockDim.x + threadIdx.x;
    if (tid >= ncol) return;
    const int b = tid >> 7;          // tid / CC
    const int c = tid & (CC - 1);    // tid % CC
    const int base = b * NL * CC + c;   // element (b, l=0, c); layer l at base + l*CC

    float arr[NL];   // phase A: rs[l]; phase B onwards: rt[l] (in-place overwrite)

    // ---------------- Phase A: bottom-up cumulative surface reflection ----
    // rs[n-1] = r[n-1]; for l=n-2..0: dd = 1/(1-rs[l+1]*r[l]);
    // rs[l] = r[l] + rs[l+1]*t[l]^2*dd.
    {
        arr[NL - 1] = r[base + (NL - 1) * CC];
        #pragma unroll
        for (int l = NL - 2; l >= 0; --l) {
            float rl = r[base + l * CC];
            float tl = t[base + l * CC];
            float dd = 1.0f / (1.0f - arr[l + 1] * rl);
            arr[l] = rl + arr[l + 1] * tl * tl * dd;
        }
    }

    // ---------------- Phase B: forward pass ------------------------------
    // Downward flux scan (consumes rs = arr[m+1]), flux_down writes,
    // absorbed down-contribution written straight to global, and the
    // top-down reflection recurrence rt[m] overwriting arr[m] in place.
    {
        float r_prev = r[base];        // r[m-1]
        float s_prev = s[base];        // s[m-1]
        float ds_prev = 1.0f / (1.0f - arr[1] * r_prev);   // ds[0]  (arr[1]=rs[1])
        float rt_prev = r_prev;        // rt[0]
        arr[0] = r_prev;               // rt[0] overwrites rs[0] (rs[0] never read)
        float flux = 0.0f;
        #pragma unroll
        for (int m = 1; m < NL; ++m) {
            float rm = r[base + m * CC];
            float sm = s[base + m * CC];
            float tm = t[base + m * CC];
            float am = a[base + m * CC];
            // downward flux: add s_down[m-1] = (s[m-1] + s[m]*r[m-1]) * ds[m-1]
            flux += (s_prev + sm * r_prev) * ds_prev;
            flux_down[base + m * CC] = flux;
            if (m < NL - 1) {
                float ds_m = 1.0f / (1.0f - arr[m + 1] * rm);   // ds[m] via rs[m+1]
                // absorbed_down[m] -> global (up part added in phase C)
                absorbed[base + m * CC] = am * (1.0f + arr[m + 1] * tm * ds_m) * flux;
                flux *= tm * ds_m;
                ds_prev = ds_m;
            } else {
                // layer n-1: absorbed_up is 0 there, final value now
                absorbed[base + m * CC] = am * flux;
            }
            // top-down reflection recurrence; rt[m] overwrites rs[m] (dead)
            float dt_m = 1.0f / (1.0f - rt_prev * rm);
            float rt_m = rm + rt_prev * tm * tm * dt_m;
            if (m < NL - 1) arr[m] = rt_m;
            rt_prev = rt_m;
            r_prev = rm;
            s_prev = sm;
        }
        flux_down[base] = 0.0f;   // flux_down[0] = 0
    }

    // ---------------- Phase C: reverse pass (upward flux) -----------------
    // dt[l] = 1/(1 - rt[l-1]*r[l]) recomputed from arr (=rt) and r.
    // absorbed[l] += up-contribution (reads phase-B write, same thread).
    {
        float flux = 0.0f;
        float r_hi = r[base + (NL - 1) * CC];   // r[k+2]
        float s_hi = s[base + (NL - 1) * CC];   // s[k+2]
        float dt_hi = 1.0f / (1.0f - arr[NL - 2] * r_hi);   // dt[n-1]
        #pragma unroll
        for (int k = NL - 3; k >= 0; --k) {
            float r1 = r[base + (k + 1) * CC];
            float s1 = s[base + (k + 1) * CC];
            float t1 = t[base + (k + 1) * CC];
            float a1 = a[base + (k + 1) * CC];
            // flux += s_up[k+2]
            flux += (s_hi + s1 * r_hi) * dt_hi;
            flux_up[base + (k + 2) * CC] = flux;
            float dt1 = 1.0f / (1.0f - arr[k] * r1);   // dt[k+1] via rt[k]
            absorbed[base + (k + 1) * CC] +=
                flux * a1 * (1.0f + t1 * arr[k] * dt1);
            flux *= t1 * dt1;
            r_hi = r1;
            s_hi = s1;
            dt_hi = dt1;
        }
        // tail: after k=0 iter, r_hi=r[1], s_hi=s[1], dt_hi=dt[1]
        float r0v = r[base];
        float s0v = s[base];
        float t0v = t[base];
        float a0v = a[base];
        float flux1 = flux + (s_hi + s0v * r_hi) * dt_hi;   // + s_up[1]
        flux_up[base + CC] = flux1;
        absorbed[base] = flux1 * a0v;                        // abs1 (down part = 0)
        flux_up[base] = flux1 * t0v + s0v;                   // flux1*t[0] + s_up[0]
    }
}

extern "C" void kernel_launch(void* const* d_in, const int* in_sizes, int n_in,
                              void* d_out, int out_size, void* d_ws, size_t ws_size,
                              hipStream_t stream) {
    const float* a = (const float*)d_in[0];
    const float* r = (const float*)d_in[1];
    const float* t = (const float*)d_in[2];
    const float* s = (const float*)d_in[3];
    const int total = in_sizes[0];       // B*N*C
    const int ncol = total / NL;         // B*C columns
    float* flux_down = (float*)d_out;
    float* flux_up = flux_down + total;
    float* absorbed = flux_up + total;
    const int threads = 256;
    const int blocks = (ncol + threads - 1) / threads;
    adding_doubling_kernel<<<blocks, threads, 0, stream>>>(
        a, r, t, s, flux_down, flux_up, absorbed, ncol);
}

// Round 2
// 685.131 us; speedup vs baseline: 1.0552x; 1.0552x over previous
//
#include <hip/hip_runtime.h>

// Adding-doubling radiative transfer: B=2048 cols, N=60 layers, C=128 channels.
// One thread per (b,c) column; all layer recurrences serial per thread.
//
// R2 changes vs R1 (which stayed at VGPR=256 / 11.6% occupancy / 483us):
//   * __launch_bounds__(256, 4): hard cap 128 VGPR -> 4 waves/SIMD (16/CU).
//     R1 showed the compiler consumes every register it is allowed for load
//     hoisting; only a hard cap raises occupancy. arr[60]+scalars fits in 128.
//   * __builtin_amdgcn_rcpf for all 1/(1-x*y): IEEE div expands to ~10
//     dependent instrs + temps; fast rcp is 1 instr, ~1 ulp (absmax budget ok).
//     Shortens the serial per-layer dependence chain ~3x.
// Kept from R1: single arr[60] (rs overwritten by rt in place), absorbed
// down-part written in phase B, += up-part in phase C (same-thread RMW).

#define NL 60
#define CC 128

__device__ __forceinline__ float frcp(float x) {
    return __builtin_amdgcn_rcpf(x);
}

__global__ __launch_bounds__(256, 4) void adding_doubling_kernel(
    const float* __restrict__ a, const float* __restrict__ r,
    const float* __restrict__ t, const float* __restrict__ s,
    float* __restrict__ flux_down, float* __restrict__ flux_up,
    float* __restrict__ absorbed, int ncol)
{
    const int tid = blockIdx.x * blockDim.x + threadIdx.x;
    if (tid >= ncol) return;
    const int b = tid >> 7;          // tid / CC
    const int c = tid & (CC - 1);    // tid % CC
    const int base = b * NL * CC + c;   // element (b, l=0, c); layer l at base + l*CC

    float arr[NL];   // phase A: rs[l]; phase B onwards: rt[l] (in-place overwrite)

    // ---------------- Phase A: bottom-up cumulative surface reflection ----
    // rs[n-1] = r[n-1]; for l=n-2..0: dd = 1/(1-rs[l+1]*r[l]);
    // rs[l] = r[l] + rs[l+1]*t[l]^2*dd.
    {
        arr[NL - 1] = r[base + (NL - 1) * CC];
        #pragma unroll
        for (int l = NL - 2; l >= 0; --l) {
            float rl = r[base + l * CC];
            float tl = t[base + l * CC];
            float dd = frcp(1.0f - arr[l + 1] * rl);
            arr[l] = rl + arr[l + 1] * tl * tl * dd;
        }
    }

    // ---------------- Phase B: forward pass ------------------------------
    // Downward flux scan (consumes rs = arr[m+1]), flux_down writes,
    // absorbed down-contribution written straight to global, and the
    // top-down reflection recurrence rt[m] overwriting arr[m] in place.
    {
        float r_prev = r[base];        // r[m-1]
        float s_prev = s[base];        // s[m-1]
        float ds_prev = frcp(1.0f - arr[1] * r_prev);   // ds[0]  (arr[1]=rs[1])
        float rt_prev = r_prev;        // rt[0]
        arr[0] = r_prev;               // rt[0] overwrites rs[0] (rs[0] never read)
        float flux = 0.0f;
        #pragma unroll
        for (int m = 1; m < NL; ++m) {
            float rm = r[base + m * CC];
            float sm = s[base + m * CC];
            float tm = t[base + m * CC];
            float am = a[base + m * CC];
            // downward flux: add s_down[m-1] = (s[m-1] + s[m]*r[m-1]) * ds[m-1]
            flux += (s_prev + sm * r_prev) * ds_prev;
            flux_down[base + m * CC] = flux;
            if (m < NL - 1) {
                float ds_m = frcp(1.0f - arr[m + 1] * rm);   // ds[m] via rs[m+1]
                // absorbed_down[m] -> global (up part added in phase C)
                absorbed[base + m * CC] = am * (1.0f + arr[m + 1] * tm * ds_m) * flux;
                flux *= tm * ds_m;
                ds_prev = ds_m;
            } else {
                // layer n-1: absorbed_up is 0 there, final value now
                absorbed[base + m * CC] = am * flux;
            }
            // top-down reflection recurrence; rt[m] overwrites rs[m] (dead)
            float dt_m = frcp(1.0f - rt_prev * rm);
            float rt_m = rm + rt_prev * tm * tm * dt_m;
            if (m < NL - 1) arr[m] = rt_m;
            rt_prev = rt_m;
            r_prev = rm;
            s_prev = sm;
        }
        flux_down[base] = 0.0f;   // flux_down[0] = 0
    }

    // ---------------- Phase C: reverse pass (upward flux) -----------------
    // dt[l] = 1/(1 - rt[l-1]*r[l]) recomputed from arr (=rt) and r.
    // absorbed[l] += up-contribution (reads phase-B write, same thread).
    {
        float flux = 0.0f;
        float r_hi = r[base + (NL - 1) * CC];   // r[k+2]
        float s_hi = s[base + (NL - 1) * CC];   // s[k+2]
        float dt_hi = frcp(1.0f - arr[NL - 2] * r_hi);   // dt[n-1]
        #pragma unroll
        for (int k = NL - 3; k >= 0; --k) {
            float r1 = r[base + (k + 1) * CC];
            float s1 = s[base + (k + 1) * CC];
            float t1 = t[base + (k + 1) * CC];
            float a1 = a[base + (k + 1) * CC];
            // flux += s_up[k+2]
            flux += (s_hi + s1 * r_hi) * dt_hi;
            flux_up[base + (k + 2) * CC] = flux;
            float dt1 = frcp(1.0f - arr[k] * r1);   // dt[k+1] via rt[k]
            absorbed[base + (k + 1) * CC] +=
                flux * a1 * (1.0f + t1 * arr[k] * dt1);
            flux *= t1 * dt1;
            r_hi = r1;
            s_hi = s1;
            dt_hi = dt1;
        }
        // tail: after k=0 iter, r_hi=r[1], s_hi=s[1], dt_hi=dt[1]
        float r0v = r[base];
        float s0v = s[base];
        float t0v = t[base];
        float a0v = a[base];
        float flux1 = flux + (s_hi + s0v * r_hi) * dt_hi;   // + s_up[1]
        flux_up[base + CC] = flux1;
        absorbed[base] = flux1 * a0v;                        // abs1 (down part = 0)
        flux_up[base] = flux1 * t0v + s0v;                   // flux1*t[0] + s_up[0]
    }
}

extern "C" void kernel_launch(void* const* d_in, const int* in_sizes, int n_in,
                              void* d_out, int out_size, void* d_ws, size_t ws_size,
                              hipStream_t stream) {
    const float* a = (const float*)d_in[0];
    const float* r = (const float*)d_in[1];
    const float* t = (const float*)d_in[2];
    const float* s = (const float*)d_in[3];
    const int total = in_sizes[0];       // B*N*C
    const int ncol = total / NL;         // B*C columns
    float* flux_down = (float*)d_out;
    float* flux_up = flux_down + total;
    float* absorbed = flux_up + total;
    const int threads = 256;
    const int blocks = (ncol + threads - 1) / threads;
    adding_doubling_kernel<<<blocks, threads, 0, stream>>>(
        a, r, t, s, flux_down, flux_up, absorbed, ncol);
}